// Round 5
// baseline (180.952 us; speedup 1.0000x reference)
//
#include <hip/hip_runtime.h>
#include <math.h>

#define N 4096
#define NFEAT 512
#define NHID 64
#define NHEADS 8
#define P_PAIRS 65536
#define CAP 128
#define LRELU_ALPHA 0.2f
#define KS1 2   // K-split for layer-1 gemm (K=512 -> 2 x 256)
#define KS2 8   // K-split for layer-2 gemm (K=512 -> 8 x 64)

// ---------------- K1: build CSR from dense adj (one pass over 67 MB) -------
__global__ __launch_bounds__(256) void build_csr(const float* __restrict__ adj,
                                                 int* __restrict__ counts,
                                                 int* __restrict__ cols) {
  int row = blockIdx.x;
  __shared__ int cnt;
  if (threadIdx.x == 0) cnt = 0;
  __syncthreads();
  const float4* arow = (const float4*)(adj + (size_t)row * N);
  for (int c4 = threadIdx.x; c4 < N / 4; c4 += 256) {
    float4 v = arow[c4];
    int base = c4 * 4;
    if (v.x > 0.f) { int k = atomicAdd(&cnt, 1); if (k < CAP) cols[(size_t)row * CAP + k] = base; }
    if (v.y > 0.f) { int k = atomicAdd(&cnt, 1); if (k < CAP) cols[(size_t)row * CAP + k] = base + 1; }
    if (v.z > 0.f) { int k = atomicAdd(&cnt, 1); if (k < CAP) cols[(size_t)row * CAP + k] = base + 2; }
    if (v.w > 0.f) { int k = atomicAdd(&cnt, 1); if (k < CAP) cols[(size_t)row * CAP + k] = base + 3; }
  }
  __syncthreads();
  if (threadIdx.x == 0) counts[row] = cnt < CAP ? cnt : CAP;
}

// ---------------- K2: templated f32 GEMM, reg-prefetch double-buffered -----
// C[m][c0+c] += A[m][kbase..] * B_eff, B_eff col c, row k at
// B[(c>>6)*bHeadStride + k*64 + (c&63)]  (covers interleaved multi-head and
// plain [K][64] weights). Output to slab blockIdx.z (K-split partials).
template <int TM, int TN, int RM, int RN>
__global__ __launch_bounds__(256) void gemm_t(const float* __restrict__ A, int lda,
                                              const float* __restrict__ B,
                                              size_t bHeadStride,
                                              float* __restrict__ P, size_t slabStride,
                                              int ldc, int kc) {
  constexpr int QA = TM * 4 / 256;  // A float4 loads per thread per chunk
  constexpr int QB = TN / 64;       // B float4 loads per thread per chunk
  __shared__ float As[2][16][TM + 4];  // [k][m], padded
  __shared__ float Bs[2][16][TN];      // [k][c]
  int t = threadIdx.x;
  int m0 = blockIdx.x * TM;
  int c0 = blockIdx.y * TN;
  int kbase = blockIdx.z * kc;
  float* Cp = P + (size_t)blockIdx.z * slabStride;
  float4 ar[QA], br[QB];
  int arow[QA], akq[QA], bkb[QB], bcq[QB];
#pragma unroll
  for (int j = 0; j < QA; ++j) {
    int q = t + j * 256;
    arow[j] = q >> 2;
    akq[j] = (q & 3) * 4;
  }
#pragma unroll
  for (int j = 0; j < QB; ++j) {
    int q = t + j * 256;
    bkb[j] = q / (TN / 4);
    bcq[j] = (q % (TN / 4)) * 4;
  }
  auto loadRegs = [&](int kb0) {
#pragma unroll
    for (int j = 0; j < QA; ++j)
      ar[j] = *(const float4*)(A + (size_t)(m0 + arow[j]) * lda + kb0 + akq[j]);
#pragma unroll
    for (int j = 0; j < QB; ++j) {
      int cg = c0 + bcq[j];
      br[j] = *(const float4*)(B + (size_t)(cg >> 6) * bHeadStride +
                               (size_t)(kb0 + bkb[j]) * 64 + (cg & 63));
    }
  };
  auto storeLds = [&](int buf) {
#pragma unroll
    for (int j = 0; j < QA; ++j) {
      As[buf][akq[j] + 0][arow[j]] = ar[j].x;
      As[buf][akq[j] + 1][arow[j]] = ar[j].y;
      As[buf][akq[j] + 2][arow[j]] = ar[j].z;
      As[buf][akq[j] + 3][arow[j]] = ar[j].w;
    }
#pragma unroll
    for (int j = 0; j < QB; ++j)
      *(float4*)(&Bs[buf][bkb[j]][bcq[j]]) = br[j];
  };
  constexpr int CPT = TN / RN;
  int tr = t / CPT, tc = t % CPT;
  float acc[RM][RN] = {};
  int nch = kc / 16;
  loadRegs(kbase);
  storeLds(0);
  __syncthreads();
  for (int c = 0; c < nch; ++c) {
    int cur = c & 1;
    if (c + 1 < nch) loadRegs(kbase + (c + 1) * 16);  // issue early
#pragma unroll
    for (int k = 0; k < 16; ++k) {
      float av[RM], bv[RN];
#pragma unroll
      for (int j = 0; j < RM / 4; ++j) {
        float4 v = *(const float4*)(&As[cur][k][tr * RM + j * 4]);
        av[j * 4 + 0] = v.x; av[j * 4 + 1] = v.y;
        av[j * 4 + 2] = v.z; av[j * 4 + 3] = v.w;
      }
#pragma unroll
      for (int j = 0; j < RN / 4; ++j) {
        float4 v = *(const float4*)(&Bs[cur][k][tc * RN + j * 4]);
        bv[j * 4 + 0] = v.x; bv[j * 4 + 1] = v.y;
        bv[j * 4 + 2] = v.z; bv[j * 4 + 3] = v.w;
      }
#pragma unroll
      for (int i = 0; i < RM; ++i)
#pragma unroll
        for (int j = 0; j < RN; ++j)
          acc[i][j] = fmaf(av[i], bv[j], acc[i][j]);
    }
    if (c + 1 < nch) {
      storeLds(cur ^ 1);  // write-late into the other buffer
      __syncthreads();
    }
  }
#pragma unroll
  for (int i = 0; i < RM; ++i)
#pragma unroll
    for (int j = 0; j < RN / 4; ++j) {
      float4 o = {acc[i][j * 4], acc[i][j * 4 + 1], acc[i][j * 4 + 2],
                  acc[i][j * 4 + 3]};
      *(float4*)(Cp + (size_t)(m0 + tr * RM + i) * ldc + c0 + tc * RN + j * 4) = o;
    }
}

// ---------------- K3a: layer-1 fused reduce + e_src/e_dst + col-sum --------
// part: KS1 slabs of [N][512] (heads interleaved). 128 blocks x 32 rows.
__global__ __launch_bounds__(256) void fuse1(const float* __restrict__ part,
                                             const float* __restrict__ a,
                                             float* __restrict__ Wh,
                                             float* __restrict__ esrc,
                                             float* __restrict__ edst,
                                             float* __restrict__ colpart) {
  int t = threadIdx.x;
  int w = t >> 6, lane = t & 63;
  int c0 = w * 128 + lane, c1 = c0 + 64;
  int h0 = 2 * w, h1 = 2 * w + 1;
  float as0 = a[h0 * 128 + lane], ad0 = a[h0 * 128 + 64 + lane];
  float as1 = a[h1 * 128 + lane], ad1 = a[h1 * 128 + 64 + lane];
  float cs0 = 0.f, cs1 = 0.f;
  int i0 = blockIdx.x * 32;
  for (int r = 0; r < 32; ++r) {
    int i = i0 + r;
    size_t base = (size_t)i * 512;
    float v0 = 0.f, v1 = 0.f;
#pragma unroll
    for (int z = 0; z < KS1; ++z) {
      v0 += part[(size_t)z * N * 512 + base + c0];
      v1 += part[(size_t)z * N * 512 + base + c1];
    }
    Wh[base + c0] = v0;
    Wh[base + c1] = v1;
    cs0 += v0;
    cs1 += v1;
    float s0 = v0 * as0, d0 = v0 * ad0;
    float s1 = v1 * as1, d1 = v1 * ad1;
#pragma unroll
    for (int off = 32; off; off >>= 1) {
      s0 += __shfl_xor(s0, off);
      d0 += __shfl_xor(d0, off);
      s1 += __shfl_xor(s1, off);
      d1 += __shfl_xor(d1, off);
    }
    if (lane == 0) {
      esrc[h0 * N + i] = s0;
      edst[h0 * N + i] = d0;
      esrc[h1 * N + i] = s1;
      edst[h1 * N + i] = d1;
    }
  }
  colpart[(size_t)blockIdx.x * 512 + c0] = cs0;
  colpart[(size_t)blockIdx.x * 512 + c1] = cs1;
}

// ---------------- K3b: layer-2 fused reduce + e + col-sum ------------------
__global__ __launch_bounds__(256) void fuse2(const float* __restrict__ part,
                                             const float* __restrict__ a,
                                             float* __restrict__ Wh,
                                             float* __restrict__ esrc,
                                             float* __restrict__ edst,
                                             float* __restrict__ colpart) {
  int t = threadIdx.x;
  int w = t >> 6, lane = t & 63;
  float as = a[lane], ad = a[64 + lane];
  float cs = 0.f;
  int i0 = blockIdx.x * 32 + w * 8;
  for (int r = 0; r < 8; ++r) {
    int i = i0 + r;
    size_t base = (size_t)i * 64;
    float v = 0.f;
#pragma unroll
    for (int z = 0; z < KS2; ++z) v += part[(size_t)z * N * 64 + base + lane];
    Wh[base + lane] = v;
    cs += v;
    float s = v * as, d = v * ad;
#pragma unroll
    for (int off = 32; off; off >>= 1) {
      s += __shfl_xor(s, off);
      d += __shfl_xor(d, off);
    }
    if (lane == 0) {
      esrc[i] = s;
      edst[i] = d;
    }
  }
  colpart[((size_t)blockIdx.x * 4 + w) * 64 + lane] = cs;
}

// ---------------- K4: fold column-sum partials (J slabs of C cols) ---------
__global__ __launch_bounds__(256) void col_sum_final(const float* __restrict__ partial,
                                                     int C, int J,
                                                     float* __restrict__ out) {
  int col = blockIdx.x * 64 + (threadIdx.x & 63);
  int q = threadIdx.x >> 6;
  int per = J / 4;
  float s = 0.f;
  for (int j = q * per; j < (q + 1) * per; ++j) s += partial[(size_t)j * C + col];
  __shared__ float red[4][64];
  red[q][threadIdx.x & 63] = s;
  __syncthreads();
  if (q == 0)
    out[col] = red[0][threadIdx.x] + red[1][threadIdx.x] + red[2][threadIdx.x] +
               red[3][threadIdx.x];
}

// ---------------- K5a: layer-1 attention, one block (8 waves) per node -----
__global__ __launch_bounds__(512) void gat_attn_l1(const float* __restrict__ Wh,
                                                   const float* __restrict__ esrc,
                                                   const float* __restrict__ edst,
                                                   const int* __restrict__ counts,
                                                   const int* __restrict__ cols,
                                                   const float* __restrict__ sumWh,
                                                   float* __restrict__ out) {
  int i = blockIdx.x;
  int tid = threadIdx.x;
  int lane = tid & 63;
  int h = tid >> 6;
  int cnt = counts[i];
  __shared__ int jls[CAP];
  __shared__ float pls[NHEADS][CAP];
  float acc = 0.f;
  if (cnt == 0) {
    acc = sumWh[tid] * (1.0f / N);  // softmax over uniform NEG row
  } else {
    if (tid < cnt) jls[tid] = cols[(size_t)i * CAP + tid];
    __syncthreads();
    float ei = esrc[h * N + i];
    const float* ed = edst + (size_t)h * N;
    float e0 = -1e30f, e1 = -1e30f;
    if (lane < cnt) {
      float e = ei + ed[jls[lane]];
      e0 = (e > 0.f) ? e : LRELU_ALPHA * e;
    }
    if (lane + 64 < cnt) {
      float e = ei + ed[jls[lane + 64]];
      e1 = (e > 0.f) ? e : LRELU_ALPHA * e;
    }
    float m = fmaxf(e0, e1);
#pragma unroll
    for (int off = 32; off; off >>= 1) m = fmaxf(m, __shfl_xor(m, off));
    float p0 = (lane < cnt) ? __expf(e0 - m) : 0.f;
    float p1 = (lane + 64 < cnt) ? __expf(e1 - m) : 0.f;
    float ssum = p0 + p1;
#pragma unroll
    for (int off = 32; off; off >>= 1) ssum += __shfl_xor(ssum, off);
    pls[h][lane] = p0;
    pls[h][lane + 64] = p1;  // own-wave write->read
    int k = 0;
    for (; k + 8 <= cnt; k += 8) {  // 8 gathers in flight
      int j0 = jls[k + 0], j1 = jls[k + 1], j2 = jls[k + 2], j3 = jls[k + 3];
      int j4 = jls[k + 4], j5 = jls[k + 5], j6 = jls[k + 6], j7 = jls[k + 7];
      float4 pa = *(const float4*)(&pls[h][k]);
      float4 pb = *(const float4*)(&pls[h][k + 4]);
      float v0 = Wh[((size_t)j0 << 9) + tid];
      float v1 = Wh[((size_t)j1 << 9) + tid];
      float v2 = Wh[((size_t)j2 << 9) + tid];
      float v3 = Wh[((size_t)j3 << 9) + tid];
      float v4 = Wh[((size_t)j4 << 9) + tid];
      float v5 = Wh[((size_t)j5 << 9) + tid];
      float v6 = Wh[((size_t)j6 << 9) + tid];
      float v7 = Wh[((size_t)j7 << 9) + tid];
      acc = fmaf(pa.x, v0, acc);
      acc = fmaf(pa.y, v1, acc);
      acc = fmaf(pa.z, v2, acc);
      acc = fmaf(pa.w, v3, acc);
      acc = fmaf(pb.x, v4, acc);
      acc = fmaf(pb.y, v5, acc);
      acc = fmaf(pb.z, v6, acc);
      acc = fmaf(pb.w, v7, acc);
    }
    for (; k < cnt; ++k)
      acc = fmaf(pls[h][k], Wh[((size_t)jls[k] << 9) + tid], acc);
    acc /= ssum;
  }
  acc = (acc > 0.f) ? acc : expm1f(acc);  // ELU
  out[((size_t)i << 9) + tid] = acc;
}

// ---------------- K5b: layer-2 attention, one wave per node ----------------
__global__ __launch_bounds__(256) void gat_attn_l2(const float* __restrict__ Wh,
                                                   const float* __restrict__ esrc,
                                                   const float* __restrict__ edst,
                                                   const int* __restrict__ counts,
                                                   const int* __restrict__ cols,
                                                   const float* __restrict__ sumWh,
                                                   float* __restrict__ out) {
  int wv = threadIdx.x >> 6;
  int lane = threadIdx.x & 63;
  int i = (blockIdx.x << 2) + wv;
  int cnt = counts[i];
  __shared__ int jls[4][CAP];
  __shared__ float pls[4][CAP];
  float acc = 0.f;
  if (cnt == 0) {
    acc = sumWh[lane] * (1.0f / N);
  } else {
    const int* cl = cols + (size_t)i * CAP;
    if (lane < cnt) jls[wv][lane] = cl[lane];
    if (lane + 64 < cnt) jls[wv][lane + 64] = cl[lane + 64];
    float ei = esrc[i];
    float e0 = -1e30f, e1 = -1e30f;
    if (lane < cnt) {
      float e = ei + edst[jls[wv][lane]];
      e0 = (e > 0.f) ? e : LRELU_ALPHA * e;
    }
    if (lane + 64 < cnt) {
      float e = ei + edst[jls[wv][lane + 64]];
      e1 = (e > 0.f) ? e : LRELU_ALPHA * e;
    }
    float m = fmaxf(e0, e1);
#pragma unroll
    for (int off = 32; off; off >>= 1) m = fmaxf(m, __shfl_xor(m, off));
    float p0 = (lane < cnt) ? __expf(e0 - m) : 0.f;
    float p1 = (lane + 64 < cnt) ? __expf(e1 - m) : 0.f;
    float ssum = p0 + p1;
#pragma unroll
    for (int off = 32; off; off >>= 1) ssum += __shfl_xor(ssum, off);
    pls[wv][lane] = p0;
    pls[wv][lane + 64] = p1;
    int k = 0;
    for (; k + 4 <= cnt; k += 4) {
      int ja = jls[wv][k + 0], jb = jls[wv][k + 1];
      int jc = jls[wv][k + 2], jd = jls[wv][k + 3];
      float4 pq = *(const float4*)(&pls[wv][k]);
      float va = Wh[((size_t)ja << 6) + lane];
      float vb = Wh[((size_t)jb << 6) + lane];
      float vc = Wh[((size_t)jc << 6) + lane];
      float vd = Wh[((size_t)jd << 6) + lane];
      acc = fmaf(pq.x, va, acc);
      acc = fmaf(pq.y, vb, acc);
      acc = fmaf(pq.z, vc, acc);
      acc = fmaf(pq.w, vd, acc);
    }
    for (; k < cnt; ++k)
      acc = fmaf(pls[wv][k], Wh[((size_t)jls[wv][k] << 6) + lane], acc);
    acc /= ssum;
  }
  acc = (acc > 0.f) ? acc : expm1f(acc);  // ELU
  out[((size_t)i << 6) + lane] = acc;
}

// ---------------- K6a: score GEMM g = hf @ W_score (K=64, wave-per-row) ----
__global__ __launch_bounds__(256) void gemm_row64(const float* __restrict__ A,
                                                  const float* __restrict__ B,
                                                  float* __restrict__ C) {
  __shared__ float Bs[64][64];
  int t = threadIdx.x;
#pragma unroll
  for (int j = 0; j < 4; ++j) {
    int q = t + j * 256;
    int k = q >> 4, cq = (q & 15) * 4;
    *(float4*)(&Bs[k][cq]) = *(const float4*)(B + k * 64 + cq);
  }
  __syncthreads();
  int lane = t & 63, w = t >> 6;
  int r = blockIdx.x * 4 + w;
  float hv = A[(size_t)r * 64 + lane];
  float acc = 0.f;
#pragma unroll
  for (int k = 0; k < 64; ++k) {
    float a = __shfl(hv, k);
    acc = fmaf(a, Bs[k][lane], acc);
  }
  C[(size_t)r * 64 + lane] = acc;
}

// ---------------- K6b: pairwise bilinear scores (4 pairs/wave, float4) -----
__global__ __launch_bounds__(256) void score_quad(const float* __restrict__ g,
                                                  const float* __restrict__ hf,
                                                  const int* __restrict__ p1,
                                                  const int* __restrict__ p2,
                                                  float* __restrict__ out) {
  int w = threadIdx.x >> 6;
  int lane = threadIdx.x & 63;
  int sub = lane >> 4, sl = lane & 15;
  int p = (((blockIdx.x << 2) + w) << 2) + sub;
  int i1 = p1[p], i2 = p2[p];
  float4 ga = *(const float4*)(g + ((size_t)i1 << 6) + sl * 4);
  float4 hb = *(const float4*)(hf + ((size_t)i2 << 6) + sl * 4);
  float v = ga.x * hb.x + ga.y * hb.y + ga.z * hb.z + ga.w * hb.w;
#pragma unroll
  for (int off = 8; off; off >>= 1) v += __shfl_xor(v, off);
  if (sl == 0) out[p] = v;
}

extern "C" void kernel_launch(void* const* d_in, const int* in_sizes, int n_in,
                              void* d_out, int out_size, void* d_ws, size_t ws_size,
                              hipStream_t stream) {
  const float* x       = (const float*)d_in[0];
  const float* adj     = (const float*)d_in[1];
  const float* W_heads = (const float*)d_in[2];
  const float* a_heads = (const float*)d_in[3];
  const float* W_out   = (const float*)d_in[4];
  const float* a_out   = (const float*)d_in[5];
  const float* W_score = (const float*)d_in[6];
  const int* p1        = (const int*)d_in[7];
  const int* p2        = (const int*)d_in[8];
  float* out           = (float*)d_out;

  char* ws = (char*)d_ws;
  size_t off = 0;
  auto alloc = [&](size_t bytes) -> void* {
    void* p = ws + off;
    off += (bytes + 255) & ~(size_t)255;
    return p;
  };
  int*   counts = (int*)alloc((size_t)N * 4);
  int*   cols   = (int*)alloc((size_t)N * CAP * 4);
  float* Wh1    = (float*)alloc((size_t)N * 512 * 4);   // [N][8*64] interleaved
  float* es1    = (float*)alloc((size_t)NHEADS * N * 4);
  float* ed1    = (float*)alloc((size_t)NHEADS * N * 4);
  float* sum1   = (float*)alloc((size_t)512 * 4);
  float* partA  = (float*)alloc((size_t)KS1 * N * 512 * 4);  // 16 MB
  float* cpart1 = (float*)alloc((size_t)128 * 512 * 4);
  float* h1     = (float*)alloc((size_t)N * 512 * 4);
  float* Wh2    = (float*)alloc((size_t)N * 64 * 4);
  float* es2    = (float*)alloc((size_t)N * 4);
  float* ed2    = (float*)alloc((size_t)N * 4);
  float* sum2   = (float*)alloc((size_t)64 * 4);
  float* partB  = (float*)alloc((size_t)KS2 * N * 64 * 4);   // 8 MB
  float* cpart2 = (float*)alloc((size_t)512 * 64 * 4);
  float* hf     = (float*)alloc((size_t)N * 64 * 4);
  float* g      = (float*)alloc((size_t)N * 64 * 4);

  // adjacency -> CSR (shared by both layers)
  build_csr<<<N, 256, 0, stream>>>(adj, counts, cols);

  // ---- layer 1: x[4096x512] @ B_eff[512x512] (heads interleaved) ----
  gemm_t<64, 128, 4, 8><<<dim3(N / 64, 4, KS1), 256, 0, stream>>>(
      x, NFEAT, W_heads, (size_t)NFEAT * 64, partA, (size_t)N * 512, 512,
      NFEAT / KS1);
  fuse1<<<128, 256, 0, stream>>>(partA, a_heads, Wh1, es1, ed1, cpart1);
  col_sum_final<<<8, 256, 0, stream>>>(cpart1, 512, 128, sum1);
  gat_attn_l1<<<N, 512, 0, stream>>>(Wh1, es1, ed1, counts, cols, sum1, h1);

  // ---- layer 2: h1[4096x512] @ W_out[512x64] ----
  gemm_t<128, 64, 8, 4><<<dim3(N / 128, 1, KS2), 256, 0, stream>>>(
      h1, 512, W_out, 0, partB, (size_t)N * 64, 64, 512 / KS2);
  fuse2<<<128, 256, 0, stream>>>(partB, a_out, Wh2, es2, ed2, cpart2);
  col_sum_final<<<1, 256, 0, stream>>>(cpart2, 64, 512, sum2);
  gat_attn_l2<<<N / 4, 256, 0, stream>>>(Wh2, es2, ed2, counts, cols, sum2, hf);

  // ---- pairwise scores ----
  gemm_row64<<<N / 4, 256, 0, stream>>>(hf, W_score, g);
  score_quad<<<P_PAIRS / 16, 256, 0, stream>>>(g, hf, p1, p2, out);
}